// Round 4
// baseline (381.231 us; speedup 1.0000x reference)
//
#include <hip/hip_runtime.h>
#include <hip/hip_bf16.h>
#include <math.h>

typedef __bf16 bf16x8 __attribute__((ext_vector_type(8)));
typedef float f32x4 __attribute__((ext_vector_type(4)));

#define MFMA16(A, B, C) __builtin_amdgcn_mfma_f32_16x16x32_bf16(A, B, C, 0, 0, 0)

// Problem constants
static constexpr int Bc   = 2;
static constexpr int Tc   = 2048;
static constexpr int Cc   = 1024;
static constexpr int Hc   = 16;
static constexpr int Dc   = 64;
static constexpr int Mrows = Bc * Tc;   // 4096
static constexpr int N3    = 3 * Cc;    // 3072

// ---------------------------------------------------------------------------
// x (f32) -> bf16, 8 elements per thread
// ---------------------------------------------------------------------------
__global__ __launch_bounds__(256) void convert_x(
    const float* __restrict__ src, __bf16* __restrict__ dst, int n) {
  const int i0 = (blockIdx.x * 256 + threadIdx.x) * 8;
  if (i0 >= n) return;
  f32x4 a = *(const f32x4*)(src + i0);
  f32x4 b = *(const f32x4*)(src + i0 + 4);
  bf16x8 v;
#pragma unroll
  for (int j = 0; j < 4; ++j) { v[j] = (__bf16)a[j]; v[4 + j] = (__bf16)b[j]; }
  *(bf16x8*)(dst + i0) = v;
}

// ---------------------------------------------------------------------------
// Weight transpose f32->bf16 (+ optional qkv column permutation).
// dst[n][k] = src[k][col(n)];  col(n) = h*192 + d*3 + three when perm=1
// (deinterleaves einops 'b t (h d three)' so qkv_p columns are q|k|v, h-major)
// ---------------------------------------------------------------------------
__global__ __launch_bounds__(256) void transpose_perm(
    const float* __restrict__ src, __bf16* __restrict__ dst,
    int K, int N, int perm) {
  __shared__ __bf16 tile[32][33];
  const int n0 = blockIdx.x * 32;
  const int k0 = blockIdx.y * 32;
  const int x = threadIdx.x & 31;
  const int y = threadIdx.x >> 5;  // 0..7
  {
    int n = n0 + x;
    int col = n;
    if (perm) {
      int three = n >> 10, rem = n & 1023;
      int h = rem >> 6, d = rem & 63;
      col = h * 192 + d * 3 + three;
    }
#pragma unroll
    for (int r = 0; r < 4; ++r) {
      int k = k0 + y + r * 8;
      tile[y + r * 8][x] = (__bf16)src[(size_t)k * N + col];
    }
  }
  __syncthreads();
#pragma unroll
  for (int r = 0; r < 4; ++r) {
    int n = n0 + y + r * 8;
    dst[(size_t)n * K + k0 + x] = tile[x][y + r * 8];
  }
}

// ---------------------------------------------------------------------------
// V transpose: vt[(b*H+h)][d][t] = qkv_p[(b*T+t)][2048 + h*64 + d]
// ---------------------------------------------------------------------------
__global__ __launch_bounds__(256) void v_transpose(
    const __bf16* __restrict__ qkvp, __bf16* __restrict__ vt) {
  __shared__ __bf16 tile[32][33];
  const int t0 = blockIdx.x * 32;
  const int d0 = blockIdx.y * 32;
  const int bh = blockIdx.z;
  const int b = bh >> 4, h = bh & 15;
  const int x = threadIdx.x & 31;
  const int y = threadIdx.x >> 5;
#pragma unroll
  for (int r = 0; r < 4; ++r) {
    int t = t0 + y + r * 8;
    tile[y + r * 8][x] =
        qkvp[(size_t)(b * Tc + t) * N3 + 2 * Cc + h * 64 + d0 + x];
  }
  __syncthreads();
#pragma unroll
  for (int r = 0; r < 4; ++r) {
    int d = d0 + y + r * 8;
    vt[((size_t)bh * 64 + d) * Tc + t0 + x] = tile[x][y + r * 8];
  }
}

// ---------------------------------------------------------------------------
// NT GEMM: C[m][n] = sum_k A[m][k] * Bt[n][k]  (+bias[n]), bf16 in, fp32 acc
// 128x128 block tile, 4 waves (2x2), each wave 64x64 = 4x4 MFMA tiles, BK=32.
// F32OUT selects output element type (bf16 intermediate vs f32 final).
// ---------------------------------------------------------------------------
template <bool F32OUT>
__global__ __launch_bounds__(256) void gemm_nt(
    const __bf16* __restrict__ A, const __bf16* __restrict__ Bt,
    void* __restrict__ Cmat, const float* __restrict__ bias,
    int M, int N, int K, int ldc) {
  __shared__ __align__(16) __bf16 As[128 * 32];
  __shared__ __align__(16) __bf16 Bs[128 * 32];
  const int n0 = blockIdx.x * 128, m0 = blockIdx.y * 128;
  const int tid = threadIdx.x;
  const int wave = tid >> 6, lane = tid & 63;
  const int quad = lane >> 4, l16 = lane & 15;
  const int wm = (wave >> 1) * 64, wn = (wave & 1) * 64;
  const int srow = lane >> 2, scol = (lane & 3) * 8;

  f32x4 acc[4][4] = {};

  for (int k0 = 0; k0 < K; k0 += 32) {
    __syncthreads();
#pragma unroll
    for (int c = 0; c < 2; ++c) {
      int row = (wave + c * 4) * 16 + srow;
      *(bf16x8*)(&As[row * 32 + scol]) =
          *(const bf16x8*)(A + (size_t)(m0 + row) * K + k0 + scol);
      *(bf16x8*)(&Bs[row * 32 + scol]) =
          *(const bf16x8*)(Bt + (size_t)(n0 + row) * K + k0 + scol);
    }
    __syncthreads();
    bf16x8 af[4], bfr[4];
#pragma unroll
    for (int i = 0; i < 4; ++i) {
      af[i]  = *(const bf16x8*)(&As[(wm + i * 16 + l16) * 32 + quad * 8]);
      bfr[i] = *(const bf16x8*)(&Bs[(wn + i * 16 + l16) * 32 + quad * 8]);
    }
#pragma unroll
    for (int mi = 0; mi < 4; ++mi)
#pragma unroll
      for (int ni = 0; ni < 4; ++ni)
        acc[mi][ni] = MFMA16(af[mi], bfr[ni], acc[mi][ni]);
  }

#pragma unroll
  for (int ni = 0; ni < 4; ++ni) {
    int col = n0 + wn + ni * 16 + l16;
    float bv = bias ? bias[col] : 0.0f;
#pragma unroll
    for (int mi = 0; mi < 4; ++mi)
#pragma unroll
      for (int r = 0; r < 4; ++r) {
        int row = m0 + wm + mi * 16 + quad * 4 + r;
        float v = acc[mi][ni][r] + bv;
        if (F32OUT)
          ((float*)Cmat)[(size_t)row * ldc + col] = v;
        else
          ((__bf16*)Cmat)[(size_t)row * ldc + col] = (__bf16)v;
      }
  }
}

// ---------------------------------------------------------------------------
// Causal flash attention. Grid: (T/64, B*H). Block: 256 thr = 4 waves.
// Wave w owns q-rows [q0+16w, q0+16w+16); loops k-chunks of 32 independently.
// ---------------------------------------------------------------------------
#define LOG2E 1.44269504088896340736f

__global__ __launch_bounds__(256) void attn_kernel(
    const __bf16* __restrict__ qkv,  // [4096][3072] cols: q|k|v, h*64+d
    const __bf16* __restrict__ vt,   // [B*H][64][2048]
    __bf16* __restrict__ obuf) {     // [4096][1024] cols h*64+d
  __shared__ __align__(16) __bf16 plds[4][16 * 40];  // per-wave P 16x32, stride 40

  const int q0 = (gridDim.x - 1 - blockIdx.x) * 64;  // heavy tiles dispatch first
  const int bh = blockIdx.y;
  const int b = bh >> 4, h = bh & 15;
  const int tid = threadIdx.x;
  const int wave = tid >> 6, lane = tid & 63;
  const int quad = lane >> 4, l16 = lane & 15;
  const int qw = q0 + wave * 16;

  const __bf16* qbase = qkv + (size_t)(b * Tc) * N3 + h * 64;
  const __bf16* kbase = qbase + Cc;
  const __bf16* vtb = vt + (size_t)bh * 64 * Tc;
  __bf16* pl = &plds[wave][0];

  // Q fragments (held for the whole k-loop)
  bf16x8 aQ0 = *(const bf16x8*)(qbase + (size_t)(qw + l16) * N3 + quad * 8);
  bf16x8 aQ1 = *(const bf16x8*)(qbase + (size_t)(qw + l16) * N3 + 32 + quad * 8);

  f32x4 accO[4] = {};
  float mrow[4], lrow[4];
#pragma unroll
  for (int r = 0; r < 4; ++r) { mrow[r] = -INFINITY; lrow[r] = 0.0f; }

  const int kend = qw + 16;
  for (int kc = 0; kc < kend; kc += 32) {
    // ---- S = Q K^T (two 16x16 tiles) ----
    f32x4 s[2];
#pragma unroll
    for (int kt = 0; kt < 2; ++kt) {
      const __bf16* kr = kbase + (size_t)(kc + kt * 16 + l16) * N3;
      bf16x8 bK0 = *(const bf16x8*)(kr + quad * 8);
      bf16x8 bK1 = *(const bf16x8*)(kr + 32 + quad * 8);
      f32x4 a = {};
      a = MFMA16(aQ0, bK0, a);
      a = MFMA16(aQ1, bK1, a);
      s[kt] = a;
    }
    // ---- scale, causal mask, row max ----
    float vmax[4];
#pragma unroll
    for (int r = 0; r < 4; ++r) {
      int qrow = qw + quad * 4 + r;
      float s0 = s[0][r] * 0.125f;
      float s1 = s[1][r] * 0.125f;
      if (kc + l16 > qrow)      s0 = -INFINITY;
      if (kc + 16 + l16 > qrow) s1 = -INFINITY;
      s[0][r] = s0; s[1][r] = s1;
      vmax[r] = fmaxf(s0, s1);
    }
#pragma unroll
    for (int mask = 1; mask <= 8; mask <<= 1)
#pragma unroll
      for (int r = 0; r < 4; ++r)
        vmax[r] = fmaxf(vmax[r], __shfl_xor(vmax[r], mask));
    // ---- online softmax update ----
    float alpha[4], psum[4];
#pragma unroll
    for (int r = 0; r < 4; ++r) {
      float mnew = fmaxf(mrow[r], vmax[r]);
      alpha[r] = exp2f((mrow[r] - mnew) * LOG2E);
      mrow[r] = mnew;
      float p0 = exp2f((s[0][r] - mnew) * LOG2E);
      float p1 = exp2f((s[1][r] - mnew) * LOG2E);
      s[0][r] = p0; s[1][r] = p1;
      psum[r] = p0 + p1;
    }
#pragma unroll
    for (int mask = 1; mask <= 8; mask <<= 1)
#pragma unroll
      for (int r = 0; r < 4; ++r)
        psum[r] += __shfl_xor(psum[r], mask);
#pragma unroll
    for (int r = 0; r < 4; ++r) lrow[r] = lrow[r] * alpha[r] + psum[r];
#pragma unroll
    for (int dt = 0; dt < 4; ++dt)
#pragma unroll
      for (int r = 0; r < 4; ++r) accO[dt][r] *= alpha[r];
    // ---- P: C-layout -> A-layout via wave-private LDS ----
#pragma unroll
    for (int kt = 0; kt < 2; ++kt)
#pragma unroll
      for (int r = 0; r < 4; ++r)
        pl[(quad * 4 + r) * 40 + kt * 16 + l16] = (__bf16)s[kt][r];
    __threadfence_block();  // order LDS write->read (same wave, private buffer)
    bf16x8 aP = *(const bf16x8*)(pl + l16 * 40 + quad * 8);
    // ---- O += P V ----
#pragma unroll
    for (int dt = 0; dt < 4; ++dt) {
      bf16x8 bV = *(const bf16x8*)(vtb + (size_t)(dt * 16 + l16) * Tc + kc + quad * 8);
      accO[dt] = MFMA16(aP, bV, accO[dt]);
    }
  }

  // ---- epilogue ----
  __bf16* orow = obuf + (size_t)(b * Tc) * Cc + h * 64;
#pragma unroll
  for (int r = 0; r < 4; ++r) {
    float inv = 1.0f / lrow[r];
    int qrow = qw + quad * 4 + r;
#pragma unroll
    for (int dt = 0; dt < 4; ++dt)
      orow[(size_t)qrow * Cc + dt * 16 + l16] = (__bf16)(accO[dt][r] * inv);
  }
}

// ---------------------------------------------------------------------------
extern "C" void kernel_launch(void* const* d_in, const int* in_sizes, int n_in,
                              void* d_out, int out_size, void* d_ws, size_t ws_size,
                              hipStream_t stream) {
  const float* x      = (const float*)d_in[0];  // [2,2048,1024] f32
  const float* w_qkv  = (const float*)d_in[1];  // [1024,3072]   f32
  const float* w_proj = (const float*)d_in[2];  // [1024,1024]   f32
  const float* b_proj = (const float*)d_in[3];  // [1024]        f32

  // Output dtype dispatch: query the allocation size of d_out. A host-side
  // bookkeeping call; no stream interaction, graph-capture-neutral.
  // bytes >= 4*out_size -> f32 output; else bf16. Default f32 per harness doc.
  bool f32out = true;
  {
    size_t out_bytes = 0;
    if (hipMemPtrGetInfo(d_out, &out_bytes) == hipSuccess && out_bytes != 0)
      f32out = out_bytes >= (size_t)out_size * 4;
  }

  // ws layout (bf16 elems), 56 MB total — R2-evidenced safe footprint.
  __bf16* xb     = (__bf16*)d_ws;                       // 4096*1024   [0,8M)
  __bf16* wqkvT  = xb + (size_t)Mrows * Cc;             // 3072*1024   [8M,14M)
  __bf16* wprojT = wqkvT + (size_t)N3 * Cc;             // 1024*1024   [14M,16M)
  __bf16* qkvp   = wprojT + (size_t)Cc * Cc;            // 4096*3072   [16M,40M)
  __bf16* vt     = qkvp + (size_t)Mrows * N3;           // 32*64*2048  [40M,48M)
  __bf16* obuf   = vt + (size_t)Bc * Hc * Dc * Tc;      // 4096*1024   [48M,56M)

  convert_x<<<(Mrows * Cc) / (256 * 8), 256, 0, stream>>>(x, xb, Mrows * Cc);
  transpose_perm<<<dim3(N3 / 32, Cc / 32), 256, 0, stream>>>(
      w_qkv, wqkvT, Cc, N3, 1);
  transpose_perm<<<dim3(Cc / 32, Cc / 32), 256, 0, stream>>>(
      w_proj, wprojT, Cc, Cc, 0);
  gemm_nt<false><<<dim3(N3 / 128, Mrows / 128), 256, 0, stream>>>(
      xb, wqkvT, qkvp, nullptr, Mrows, N3, Cc, N3);
  v_transpose<<<dim3(Tc / 32, 2, Bc * Hc), 256, 0, stream>>>(qkvp, vt);
  attn_kernel<<<dim3(Tc / 64, Bc * Hc), 256, 0, stream>>>(qkvp, vt, obuf);
  if (f32out) {
    gemm_nt<true><<<dim3(Cc / 128, Mrows / 128), 256, 0, stream>>>(
        obuf, wprojT, d_out, b_proj, Mrows, Cc, Cc, Cc);
  } else {
    gemm_nt<false><<<dim3(Cc / 128, Mrows / 128), 256, 0, stream>>>(
        obuf, wprojT, d_out, b_proj, Mrows, Cc, Cc, Cc);
  }
}

// Round 5
// 278.746 us; speedup vs baseline: 1.3677x; 1.3677x over previous
//
#include <hip/hip_runtime.h>
#include <hip/hip_bf16.h>
#include <math.h>

typedef __bf16 bf16x8 __attribute__((ext_vector_type(8)));
typedef float f32x4 __attribute__((ext_vector_type(4)));

#define MFMA16(A, B, C) __builtin_amdgcn_mfma_f32_16x16x32_bf16(A, B, C, 0, 0, 0)

// Problem constants
static constexpr int Bc   = 2;
static constexpr int Tc   = 2048;
static constexpr int Cc   = 1024;
static constexpr int Hc   = 16;
static constexpr int Dc   = 64;
static constexpr int Mrows = Bc * Tc;   // 4096
static constexpr int N3    = 3 * Cc;    // 3072

// ---------------------------------------------------------------------------
// x (f32) -> bf16, 8 elements per thread
// ---------------------------------------------------------------------------
__global__ __launch_bounds__(256) void convert_x(
    const float* __restrict__ src, __bf16* __restrict__ dst, int n) {
  const int i0 = (blockIdx.x * 256 + threadIdx.x) * 8;
  if (i0 >= n) return;
  f32x4 a = *(const f32x4*)(src + i0);
  f32x4 b = *(const f32x4*)(src + i0 + 4);
  bf16x8 v;
#pragma unroll
  for (int j = 0; j < 4; ++j) { v[j] = (__bf16)a[j]; v[4 + j] = (__bf16)b[j]; }
  *(bf16x8*)(dst + i0) = v;
}

// ---------------------------------------------------------------------------
// Weight transpose f32->bf16 (+ optional qkv column permutation).
// dst[n][k] = src[k][col(n)];  col(n) = h*192 + d*3 + three when perm=1
// ---------------------------------------------------------------------------
__global__ __launch_bounds__(256) void transpose_perm(
    const float* __restrict__ src, __bf16* __restrict__ dst,
    int K, int N, int perm) {
  __shared__ __bf16 tile[32][33];
  const int n0 = blockIdx.x * 32;
  const int k0 = blockIdx.y * 32;
  const int x = threadIdx.x & 31;
  const int y = threadIdx.x >> 5;  // 0..7
  {
    int n = n0 + x;
    int col = n;
    if (perm) {
      int three = n >> 10, rem = n & 1023;
      int h = rem >> 6, d = rem & 63;
      col = h * 192 + d * 3 + three;
    }
#pragma unroll
    for (int r = 0; r < 4; ++r) {
      int k = k0 + y + r * 8;
      tile[y + r * 8][x] = (__bf16)src[(size_t)k * N + col];
    }
  }
  __syncthreads();
#pragma unroll
  for (int r = 0; r < 4; ++r) {
    int n = n0 + y + r * 8;
    dst[(size_t)n * K + k0 + x] = tile[x][y + r * 8];
  }
}

// ---------------------------------------------------------------------------
// V transpose: vt[(b*H+h)][d][t] = qkv_p[(b*T+t)][2048 + h*64 + d]
// ---------------------------------------------------------------------------
__global__ __launch_bounds__(256) void v_transpose(
    const __bf16* __restrict__ qkvp, __bf16* __restrict__ vt) {
  __shared__ __bf16 tile[32][33];
  const int t0 = blockIdx.x * 32;
  const int d0 = blockIdx.y * 32;
  const int bh = blockIdx.z;
  const int b = bh >> 4, h = bh & 15;
  const int x = threadIdx.x & 31;
  const int y = threadIdx.x >> 5;
#pragma unroll
  for (int r = 0; r < 4; ++r) {
    int t = t0 + y + r * 8;
    tile[y + r * 8][x] =
        qkvp[(size_t)(b * Tc + t) * N3 + 2 * Cc + h * 64 + d0 + x];
  }
  __syncthreads();
#pragma unroll
  for (int r = 0; r < 4; ++r) {
    int d = d0 + y + r * 8;
    vt[((size_t)bh * 64 + d) * Tc + t0 + x] = tile[x][y + r * 8];
  }
}

// ---------------------------------------------------------------------------
// NT GEMM: C[m][n] = sum_k A[m][k] * Bt[n][k]  (+bias[n]), bf16 in, fp32 acc
// 128x128 block tile, 4 waves (2x2), each wave 64x64 = 4x4 MFMA tiles, BK=32.
// ---------------------------------------------------------------------------
template <bool F32OUT>
__global__ __launch_bounds__(256) void gemm_nt(
    const __bf16* __restrict__ A, const __bf16* __restrict__ Bt,
    void* __restrict__ Cmat, const float* __restrict__ bias,
    int M, int N, int K, int ldc) {
  __shared__ __align__(16) __bf16 As[128 * 32];
  __shared__ __align__(16) __bf16 Bs[128 * 32];
  const int n0 = blockIdx.x * 128, m0 = blockIdx.y * 128;
  const int tid = threadIdx.x;
  const int wave = tid >> 6, lane = tid & 63;
  const int quad = lane >> 4, l16 = lane & 15;
  const int wm = (wave >> 1) * 64, wn = (wave & 1) * 64;
  const int srow = lane >> 2, scol = (lane & 3) * 8;

  f32x4 acc[4][4] = {};

  for (int k0 = 0; k0 < K; k0 += 32) {
    __syncthreads();
#pragma unroll
    for (int c = 0; c < 2; ++c) {
      int row = (wave + c * 4) * 16 + srow;
      *(bf16x8*)(&As[row * 32 + scol]) =
          *(const bf16x8*)(A + (size_t)(m0 + row) * K + k0 + scol);
      *(bf16x8*)(&Bs[row * 32 + scol]) =
          *(const bf16x8*)(Bt + (size_t)(n0 + row) * K + k0 + scol);
    }
    __syncthreads();
    bf16x8 af[4], bfr[4];
#pragma unroll
    for (int i = 0; i < 4; ++i) {
      af[i]  = *(const bf16x8*)(&As[(wm + i * 16 + l16) * 32 + quad * 8]);
      bfr[i] = *(const bf16x8*)(&Bs[(wn + i * 16 + l16) * 32 + quad * 8]);
    }
#pragma unroll
    for (int mi = 0; mi < 4; ++mi)
#pragma unroll
      for (int ni = 0; ni < 4; ++ni)
        acc[mi][ni] = MFMA16(af[mi], bfr[ni], acc[mi][ni]);
  }

#pragma unroll
  for (int ni = 0; ni < 4; ++ni) {
    int col = n0 + wn + ni * 16 + l16;
    float bv = bias ? bias[col] : 0.0f;
#pragma unroll
    for (int mi = 0; mi < 4; ++mi)
#pragma unroll
      for (int r = 0; r < 4; ++r) {
        int row = m0 + wm + mi * 16 + quad * 4 + r;
        float v = acc[mi][ni][r] + bv;
        if (F32OUT)
          ((float*)Cmat)[(size_t)row * ldc + col] = v;
        else
          ((__bf16*)Cmat)[(size_t)row * ldc + col] = (__bf16)v;
      }
  }
}

// ---------------------------------------------------------------------------
// Block-cooperative causal flash attention.
// Grid: (T/64, B*H). Block: 256 thr = 4 waves; 64 q-rows/block (16/wave).
// Per k-chunk of 64: stage K[64x64] and V^T[64x64] in LDS (coalesced,
// stride-72 pad), all waves compute from LDS. Waves skip fully-masked chunks.
// ---------------------------------------------------------------------------
#define LOG2E 1.44269504088896340736f
static constexpr int LP = 72;  // padded LDS row stride (breaks 128B bank alias)

__global__ __launch_bounds__(256) void attn_kernel(
    const __bf16* __restrict__ qkv,  // [4096][3072] cols: q|k|v, h*64+d
    const __bf16* __restrict__ vt,   // [B*H][64][2048]
    __bf16* __restrict__ obuf) {     // [4096][1024] cols h*64+d
  __shared__ __align__(16) __bf16 Ks[64 * LP];       // [kpos][d]
  __shared__ __align__(16) __bf16 Vs[64 * LP];       // [d][t]
  __shared__ __align__(16) __bf16 plds[4][16 * LP];  // per-wave P [q][t]

  const int q0 = (gridDim.x - 1 - blockIdx.x) * 64;  // heavy tiles first
  const int bh = blockIdx.y;
  const int b = bh >> 4, h = bh & 15;
  const int tid = threadIdx.x;
  const int wave = tid >> 6, lane = tid & 63;
  const int quad = lane >> 4, l16 = lane & 15;
  const int qw = q0 + wave * 16;

  const __bf16* qbase = qkv + (size_t)(b * Tc) * N3 + h * 64;
  const __bf16* kbase = qbase + Cc;
  const __bf16* vtb = vt + (size_t)bh * 64 * Tc;
  __bf16* pl = &plds[wave][0];

  // staging indices: 4 threads per row, each 2x 16B chunks
  const int srow = tid >> 2;             // 0..63
  const int scol = (tid & 3) * 16;       // 0,16,32,48

  // Q fragments (held for the whole k-loop)
  bf16x8 aQ0 = *(const bf16x8*)(qbase + (size_t)(qw + l16) * N3 + quad * 8);
  bf16x8 aQ1 = *(const bf16x8*)(qbase + (size_t)(qw + l16) * N3 + 32 + quad * 8);

  f32x4 accO[4] = {};
  float mrow[4], lrow[4];
#pragma unroll
  for (int r = 0; r < 4; ++r) { mrow[r] = -INFINITY; lrow[r] = 0.0f; }

  const int kend = qw + 16;           // this wave's causal limit
  const int kblocks = q0 + 64;        // block-wide staged range

  for (int kc = 0; kc < kblocks; kc += 64) {
    __syncthreads();
    // ---- stage K chunk [kc..kc+64) x d[0..64) and V^T chunk d x t ----
    {
      const __bf16* kr = kbase + (size_t)(kc + srow) * N3 + scol;
      *(bf16x8*)(&Ks[srow * LP + scol])     = *(const bf16x8*)(kr);
      *(bf16x8*)(&Ks[srow * LP + scol + 8]) = *(const bf16x8*)(kr + 8);
      const __bf16* vr = vtb + (size_t)srow * Tc + kc + scol;
      *(bf16x8*)(&Vs[srow * LP + scol])     = *(const bf16x8*)(vr);
      *(bf16x8*)(&Vs[srow * LP + scol + 8]) = *(const bf16x8*)(vr + 8);
    }
    __syncthreads();
    if (kc >= kend) continue;  // wave-uniform: fully masked for this wave

    // ---- S = Q K^T (four 16x16 k-tiles) ----
    f32x4 s[4];
#pragma unroll
    for (int kt = 0; kt < 4; ++kt) {
      bf16x8 bK0 = *(const bf16x8*)(&Ks[(kt * 16 + l16) * LP + quad * 8]);
      bf16x8 bK1 = *(const bf16x8*)(&Ks[(kt * 16 + l16) * LP + 32 + quad * 8]);
      f32x4 a = {};
      a = MFMA16(aQ0, bK0, a);
      a = MFMA16(aQ1, bK1, a);
      s[kt] = a;
    }
    // ---- scale, causal mask, row max ----
    float vmax[4];
#pragma unroll
    for (int r = 0; r < 4; ++r) {
      int qrow = qw + quad * 4 + r;
      float mx = -INFINITY;
#pragma unroll
      for (int kt = 0; kt < 4; ++kt) {
        float sv = s[kt][r] * 0.125f;
        if (kc + kt * 16 + l16 > qrow) sv = -INFINITY;
        s[kt][r] = sv;
        mx = fmaxf(mx, sv);
      }
      vmax[r] = mx;
    }
#pragma unroll
    for (int mask = 1; mask <= 8; mask <<= 1)
#pragma unroll
      for (int r = 0; r < 4; ++r)
        vmax[r] = fmaxf(vmax[r], __shfl_xor(vmax[r], mask));
    // ---- online softmax update ----
    float alpha[4], psum[4];
#pragma unroll
    for (int r = 0; r < 4; ++r) {
      float mnew = fmaxf(mrow[r], vmax[r]);
      alpha[r] = exp2f((mrow[r] - mnew) * LOG2E);
      mrow[r] = mnew;
      float acc = 0.0f;
#pragma unroll
      for (int kt = 0; kt < 4; ++kt) {
        float p = exp2f((s[kt][r] - mnew) * LOG2E);
        s[kt][r] = p;
        acc += p;
      }
      psum[r] = acc;
    }
#pragma unroll
    for (int mask = 1; mask <= 8; mask <<= 1)
#pragma unroll
      for (int r = 0; r < 4; ++r)
        psum[r] += __shfl_xor(psum[r], mask);
#pragma unroll
    for (int r = 0; r < 4; ++r) lrow[r] = lrow[r] * alpha[r] + psum[r];
#pragma unroll
    for (int dt = 0; dt < 4; ++dt)
#pragma unroll
      for (int r = 0; r < 4; ++r) accO[dt][r] *= alpha[r];
    // ---- P: C-layout -> A-layout via wave-private LDS ----
#pragma unroll
    for (int kt = 0; kt < 4; ++kt)
#pragma unroll
      for (int r = 0; r < 4; ++r)
        pl[(quad * 4 + r) * LP + kt * 16 + l16] = (__bf16)s[kt][r];
    __threadfence_block();  // order LDS write->read (same wave, private buf)
    bf16x8 aP0 = *(const bf16x8*)(pl + l16 * LP + quad * 8);
    bf16x8 aP1 = *(const bf16x8*)(pl + l16 * LP + 32 + quad * 8);
    // ---- O += P V ----
#pragma unroll
    for (int dt = 0; dt < 4; ++dt) {
      bf16x8 bV0 = *(const bf16x8*)(&Vs[(dt * 16 + l16) * LP + quad * 8]);
      bf16x8 bV1 = *(const bf16x8*)(&Vs[(dt * 16 + l16) * LP + 32 + quad * 8]);
      accO[dt] = MFMA16(aP0, bV0, accO[dt]);
      accO[dt] = MFMA16(aP1, bV1, accO[dt]);
    }
  }

  // ---- epilogue ----
  __bf16* orow = obuf + (size_t)(b * Tc) * Cc + h * 64;
#pragma unroll
  for (int r = 0; r < 4; ++r) {
    float inv = 1.0f / lrow[r];
    int qrow = qw + quad * 4 + r;
#pragma unroll
    for (int dt = 0; dt < 4; ++dt)
      orow[(size_t)qrow * Cc + dt * 16 + l16] = (__bf16)(accO[dt][r] * inv);
  }
}

// ---------------------------------------------------------------------------
extern "C" void kernel_launch(void* const* d_in, const int* in_sizes, int n_in,
                              void* d_out, int out_size, void* d_ws, size_t ws_size,
                              hipStream_t stream) {
  const float* x      = (const float*)d_in[0];  // [2,2048,1024] f32
  const float* w_qkv  = (const float*)d_in[1];  // [1024,3072]   f32
  const float* w_proj = (const float*)d_in[2];  // [1024,1024]   f32
  const float* b_proj = (const float*)d_in[3];  // [1024]        f32

  // Output dtype dispatch (R4-verified: chose f32, passed).
  bool f32out = true;
  {
    size_t out_bytes = 0;
    if (hipMemPtrGetInfo(d_out, &out_bytes) == hipSuccess && out_bytes != 0)
      f32out = out_bytes >= (size_t)out_size * 4;
  }

  // ws layout (bf16 elems), 56 MB total.
  __bf16* xb     = (__bf16*)d_ws;                       // 4096*1024
  __bf16* wqkvT  = xb + (size_t)Mrows * Cc;             // 3072*1024
  __bf16* wprojT = wqkvT + (size_t)N3 * Cc;             // 1024*1024
  __bf16* qkvp   = wprojT + (size_t)Cc * Cc;            // 4096*3072
  __bf16* vt     = qkvp + (size_t)Mrows * N3;           // 32*64*2048
  __bf16* obuf   = vt + (size_t)Bc * Hc * Dc * Tc;      // 4096*1024

  convert_x<<<(Mrows * Cc) / (256 * 8), 256, 0, stream>>>(x, xb, Mrows * Cc);
  transpose_perm<<<dim3(N3 / 32, Cc / 32), 256, 0, stream>>>(
      w_qkv, wqkvT, Cc, N3, 1);
  transpose_perm<<<dim3(Cc / 32, Cc / 32), 256, 0, stream>>>(
      w_proj, wprojT, Cc, Cc, 0);
  gemm_nt<false><<<dim3(N3 / 128, Mrows / 128), 256, 0, stream>>>(
      xb, wqkvT, qkvp, nullptr, Mrows, N3, Cc, N3);
  v_transpose<<<dim3(Tc / 32, 2, Bc * Hc), 256, 0, stream>>>(qkvp, vt);
  attn_kernel<<<dim3(Tc / 64, Bc * Hc), 256, 0, stream>>>(qkvp, vt, obuf);
  if (f32out) {
    gemm_nt<true><<<dim3(Cc / 128, Mrows / 128), 256, 0, stream>>>(
        obuf, wprojT, d_out, b_proj, Mrows, Cc, Cc, Cc);
  } else {
    gemm_nt<false><<<dim3(Cc / 128, Mrows / 128), 256, 0, stream>>>(
        obuf, wprojT, d_out, b_proj, Mrows, Cc, Cc, Cc);
  }
}

// Round 6
// 244.823 us; speedup vs baseline: 1.5572x; 1.1386x over previous
//
#include <hip/hip_runtime.h>
#include <hip/hip_bf16.h>
#include <math.h>

typedef __bf16 bf16x8 __attribute__((ext_vector_type(8)));
typedef __bf16 bf16x4 __attribute__((ext_vector_type(4)));
typedef float f32x4 __attribute__((ext_vector_type(4)));

#define MFMA16(A, B, C) __builtin_amdgcn_mfma_f32_16x16x32_bf16(A, B, C, 0, 0, 0)

// Problem constants
static constexpr int Bc   = 2;
static constexpr int Tc   = 2048;
static constexpr int Cc   = 1024;
static constexpr int Hc   = 16;
static constexpr int Dc   = 64;
static constexpr int Mrows = Bc * Tc;   // 4096
static constexpr int N3    = 3 * Cc;    // 3072

// ---------------------------------------------------------------------------
// x (f32) -> bf16, 8 elements per thread
// ---------------------------------------------------------------------------
__global__ __launch_bounds__(256) void convert_x(
    const float* __restrict__ src, __bf16* __restrict__ dst, int n) {
  const int i0 = (blockIdx.x * 256 + threadIdx.x) * 8;
  if (i0 >= n) return;
  f32x4 a = *(const f32x4*)(src + i0);
  f32x4 b = *(const f32x4*)(src + i0 + 4);
  bf16x8 v;
#pragma unroll
  for (int j = 0; j < 4; ++j) { v[j] = (__bf16)a[j]; v[4 + j] = (__bf16)b[j]; }
  *(bf16x8*)(dst + i0) = v;
}

// ---------------------------------------------------------------------------
// Weight transpose f32->bf16 (+ optional qkv column permutation).
// dst[n][k] = src[k][col(n)];  col(n) = h*192 + d*3 + three when perm=1
// ---------------------------------------------------------------------------
__global__ __launch_bounds__(256) void transpose_perm(
    const float* __restrict__ src, __bf16* __restrict__ dst,
    int K, int N, int perm) {
  __shared__ __bf16 tile[32][33];
  const int n0 = blockIdx.x * 32;
  const int k0 = blockIdx.y * 32;
  const int x = threadIdx.x & 31;
  const int y = threadIdx.x >> 5;  // 0..7
  {
    int n = n0 + x;
    int col = n;
    if (perm) {
      int three = n >> 10, rem = n & 1023;
      int h = rem >> 6, d = rem & 63;
      col = h * 192 + d * 3 + three;
    }
#pragma unroll
    for (int r = 0; r < 4; ++r) {
      int k = k0 + y + r * 8;
      tile[y + r * 8][x] = (__bf16)src[(size_t)k * N + col];
    }
  }
  __syncthreads();
#pragma unroll
  for (int r = 0; r < 4; ++r) {
    int n = n0 + y + r * 8;
    dst[(size_t)n * K + k0 + x] = tile[x][y + r * 8];
  }
}

// ---------------------------------------------------------------------------
// V transpose: vt[(b*H+h)][d][t] = qkv_p[(b*T+t)][2048 + h*64 + d]
// ---------------------------------------------------------------------------
__global__ __launch_bounds__(256) void v_transpose(
    const __bf16* __restrict__ qkvp, __bf16* __restrict__ vt) {
  __shared__ __bf16 tile[32][33];
  const int t0 = blockIdx.x * 32;
  const int d0 = blockIdx.y * 32;
  const int bh = blockIdx.z;
  const int b = bh >> 4, h = bh & 15;
  const int x = threadIdx.x & 31;
  const int y = threadIdx.x >> 5;
#pragma unroll
  for (int r = 0; r < 4; ++r) {
    int t = t0 + y + r * 8;
    tile[y + r * 8][x] =
        qkvp[(size_t)(b * Tc + t) * N3 + 2 * Cc + h * 64 + d0 + x];
  }
  __syncthreads();
#pragma unroll
  for (int r = 0; r < 4; ++r) {
    int d = d0 + y + r * 8;
    vt[((size_t)bh * 64 + d) * Tc + t0 + x] = tile[x][y + r * 8];
  }
}

// ---------------------------------------------------------------------------
// NT GEMM: C[m][n] = sum_k A[m][k] * Bt[n][k]  (+bias[n]), bf16 in, fp32 acc
// 128x128 block tile, 4 waves (2x2), each wave 64x64 = 4x4 MFMA tiles, BK=32.
// ---------------------------------------------------------------------------
template <bool F32OUT>
__global__ __launch_bounds__(256) void gemm_nt(
    const __bf16* __restrict__ A, const __bf16* __restrict__ Bt,
    void* __restrict__ Cmat, const float* __restrict__ bias,
    int M, int N, int K, int ldc) {
  __shared__ __align__(16) __bf16 As[128 * 32];
  __shared__ __align__(16) __bf16 Bs[128 * 32];
  const int n0 = blockIdx.x * 128, m0 = blockIdx.y * 128;
  const int tid = threadIdx.x;
  const int wave = tid >> 6, lane = tid & 63;
  const int quad = lane >> 4, l16 = lane & 15;
  const int wm = (wave >> 1) * 64, wn = (wave & 1) * 64;
  const int srow = lane >> 2, scol = (lane & 3) * 8;

  f32x4 acc[4][4] = {};

  for (int k0 = 0; k0 < K; k0 += 32) {
    __syncthreads();
#pragma unroll
    for (int c = 0; c < 2; ++c) {
      int row = (wave + c * 4) * 16 + srow;
      *(bf16x8*)(&As[row * 32 + scol]) =
          *(const bf16x8*)(A + (size_t)(m0 + row) * K + k0 + scol);
      *(bf16x8*)(&Bs[row * 32 + scol]) =
          *(const bf16x8*)(Bt + (size_t)(n0 + row) * K + k0 + scol);
    }
    __syncthreads();
    bf16x8 af[4], bfr[4];
#pragma unroll
    for (int i = 0; i < 4; ++i) {
      af[i]  = *(const bf16x8*)(&As[(wm + i * 16 + l16) * 32 + quad * 8]);
      bfr[i] = *(const bf16x8*)(&Bs[(wn + i * 16 + l16) * 32 + quad * 8]);
    }
#pragma unroll
    for (int mi = 0; mi < 4; ++mi)
#pragma unroll
      for (int ni = 0; ni < 4; ++ni)
        acc[mi][ni] = MFMA16(af[mi], bfr[ni], acc[mi][ni]);
  }

#pragma unroll
  for (int ni = 0; ni < 4; ++ni) {
    int col = n0 + wn + ni * 16 + l16;
    float bv = bias ? bias[col] : 0.0f;
#pragma unroll
    for (int mi = 0; mi < 4; ++mi)
#pragma unroll
      for (int r = 0; r < 4; ++r) {
        int row = m0 + wm + mi * 16 + quad * 4 + r;
        float v = acc[mi][ni][r] + bv;
        if (F32OUT)
          ((float*)Cmat)[(size_t)row * ldc + col] = v;
        else
          ((__bf16*)Cmat)[(size_t)row * ldc + col] = (__bf16)v;
      }
  }
}

// ---------------------------------------------------------------------------
// Block-cooperative causal flash attention, S-TRANSPOSED formulation.
// Grid: (T/64, B*H). Block: 256 thr = 4 waves; 64 q-rows/block (16/wave).
// S^T = K·Q^T (q = lane&15, t = quad*4+reg): softmax state is one scalar
// per lane, reduction over t = 2 quad-shuffles, P^T LDS store is vector
// ds_write_b64 (conflict-free), O accumulated transposed (d x q).
// ---------------------------------------------------------------------------
#define LOG2E 1.44269504088896340736f
static constexpr int LP = 72;  // padded LDS row stride

__global__ __launch_bounds__(256) void attn_kernel(
    const __bf16* __restrict__ qkv,  // [4096][3072] cols: q|k|v, h*64+d
    const __bf16* __restrict__ vt,   // [B*H][64][2048]
    __bf16* __restrict__ obuf) {     // [4096][1024] cols h*64+d
  __shared__ __align__(16) __bf16 Ks[64 * LP];       // [kpos][d]
  __shared__ __align__(16) __bf16 Vs[64 * LP];       // [d][t]
  __shared__ __align__(16) __bf16 plds[4][16 * LP];  // per-wave P^T as [q][t]

  const int q0 = (gridDim.x - 1 - blockIdx.x) * 64;  // heavy tiles first
  const int bh = blockIdx.y;
  const int b = bh >> 4, h = bh & 15;
  const int tid = threadIdx.x;
  const int wave = tid >> 6, lane = tid & 63;
  const int quad = lane >> 4, l16 = lane & 15;
  const int qw = q0 + wave * 16;

  const __bf16* qbase = qkv + (size_t)(b * Tc) * N3 + h * 64;
  const __bf16* kbase = qbase + Cc;
  const __bf16* vtb = vt + (size_t)bh * 64 * Tc;
  __bf16* pl = &plds[wave][0];

  // staging indices: 4 threads per row, each 2x 16B chunks
  const int srow = tid >> 2;             // 0..63
  const int scol = (tid & 3) * 16;       // 0,16,32,48

  // Q fragment, used as MFMA *B* operand: B[k=d][n=q] = Q[qw+l16][d]
  bf16x8 bQ0 = *(const bf16x8*)(qbase + (size_t)(qw + l16) * N3 + quad * 8);
  bf16x8 bQ1 = *(const bf16x8*)(qbase + (size_t)(qw + l16) * N3 + 32 + quad * 8);

  f32x4 accO[4] = {};          // O^T: [d-tile][reg], col q = l16
  float m_i = -INFINITY, l_i = 0.0f;  // per-lane (q = qw+l16), quad-replicated

  const int kend = qw + 16;           // this wave's causal limit
  const int kblocks = q0 + 64;        // block-wide staged range
  const int qcol = qw + l16;

  for (int kc = 0; kc < kblocks; kc += 64) {
    __syncthreads();
    // ---- stage K chunk [kc..kc+64) x d and V^T chunk d x t ----
    {
      const __bf16* kr = kbase + (size_t)(kc + srow) * N3 + scol;
      *(bf16x8*)(&Ks[srow * LP + scol])     = *(const bf16x8*)(kr);
      *(bf16x8*)(&Ks[srow * LP + scol + 8]) = *(const bf16x8*)(kr + 8);
      const __bf16* vr = vtb + (size_t)srow * Tc + kc + scol;
      *(bf16x8*)(&Vs[srow * LP + scol])     = *(const bf16x8*)(vr);
      *(bf16x8*)(&Vs[srow * LP + scol + 8]) = *(const bf16x8*)(vr + 8);
    }
    __syncthreads();
    if (kc >= kend) continue;  // wave-uniform: fully masked for this wave

    // ---- S^T = K Q^T (four 16-row t-tiles) ----
    f32x4 st[4];
#pragma unroll
    for (int kt = 0; kt < 4; ++kt) {
      bf16x8 kf0 = *(const bf16x8*)(&Ks[(kt * 16 + l16) * LP + quad * 8]);
      bf16x8 kf1 = *(const bf16x8*)(&Ks[(kt * 16 + l16) * LP + 32 + quad * 8]);
      f32x4 a = {};
      a = MFMA16(kf0, bQ0, a);
      a = MFMA16(kf1, bQ1, a);
      st[kt] = a;
    }
    // ---- scale, causal mask (t > q), per-lane max over 16 t-values ----
    float mx = -INFINITY;
#pragma unroll
    for (int kt = 0; kt < 4; ++kt)
#pragma unroll
      for (int r = 0; r < 4; ++r) {
        int t = kc + kt * 16 + quad * 4 + r;
        float sv = st[kt][r] * 0.125f;
        if (t > qcol) sv = -INFINITY;
        st[kt][r] = sv;
        mx = fmaxf(mx, sv);
      }
    // reduce over quads (t spans quads; q fixed per l16)
    mx = fmaxf(mx, __shfl_xor(mx, 16));
    mx = fmaxf(mx, __shfl_xor(mx, 32));
    // ---- online softmax update (scalar state) ----
    float mnew = fmaxf(m_i, mx);
    float alpha = exp2f((m_i - mnew) * LOG2E);
    m_i = mnew;
    float ps = 0.0f;
#pragma unroll
    for (int kt = 0; kt < 4; ++kt)
#pragma unroll
      for (int r = 0; r < 4; ++r) {
        float p = exp2f((st[kt][r] - mnew) * LOG2E);
        st[kt][r] = p;
        ps += p;
      }
    ps += __shfl_xor(ps, 16);
    ps += __shfl_xor(ps, 32);
    l_i = l_i * alpha + ps;
#pragma unroll
    for (int dt = 0; dt < 4; ++dt)
#pragma unroll
      for (int r = 0; r < 4; ++r) accO[dt][r] *= alpha;
    // ---- P^T store: 4 contiguous t per (kt) -> ds_write_b64, bank-balanced ----
#pragma unroll
    for (int kt = 0; kt < 4; ++kt) {
      bf16x4 pv;
#pragma unroll
      for (int r = 0; r < 4; ++r) pv[r] = (__bf16)st[kt][r];
      *(bf16x4*)(&pl[l16 * LP + kt * 16 + quad * 4]) = pv;
    }
    __threadfence_block();  // order LDS write->read (same wave, private buf)
    bf16x8 bP0 = *(const bf16x8*)(&pl[l16 * LP + quad * 8]);
    bf16x8 bP1 = *(const bf16x8*)(&pl[l16 * LP + 32 + quad * 8]);
    // ---- O^T += V^T P^T : A = V^T[d][t], B = P^T[t][q] ----
#pragma unroll
    for (int dt = 0; dt < 4; ++dt) {
      bf16x8 vf0 = *(const bf16x8*)(&Vs[(dt * 16 + l16) * LP + quad * 8]);
      bf16x8 vf1 = *(const bf16x8*)(&Vs[(dt * 16 + l16) * LP + 32 + quad * 8]);
      accO[dt] = MFMA16(vf0, bP0, accO[dt]);
      accO[dt] = MFMA16(vf1, bP1, accO[dt]);
    }
  }

  // ---- epilogue: lane holds O^T[d=dt*16+quad*4+r][q=qw+l16] ----
  {
    float inv = 1.0f / l_i;
    __bf16* orow = obuf + (size_t)(b * Tc + qw + l16) * Cc + h * 64;
#pragma unroll
    for (int dt = 0; dt < 4; ++dt) {
      bf16x4 ov;
#pragma unroll
      for (int r = 0; r < 4; ++r) ov[r] = (__bf16)(accO[dt][r] * inv);
      *(bf16x4*)(orow + dt * 16 + quad * 4) = ov;
    }
  }
}

// ---------------------------------------------------------------------------
extern "C" void kernel_launch(void* const* d_in, const int* in_sizes, int n_in,
                              void* d_out, int out_size, void* d_ws, size_t ws_size,
                              hipStream_t stream) {
  const float* x      = (const float*)d_in[0];  // [2,2048,1024] f32
  const float* w_qkv  = (const float*)d_in[1];  // [1024,3072]   f32
  const float* w_proj = (const float*)d_in[2];  // [1024,1024]   f32
  const float* b_proj = (const float*)d_in[3];  // [1024]        f32

  // Output dtype dispatch (R4-verified: chose f32, passed).
  bool f32out = true;
  {
    size_t out_bytes = 0;
    if (hipMemPtrGetInfo(d_out, &out_bytes) == hipSuccess && out_bytes != 0)
      f32out = out_bytes >= (size_t)out_size * 4;
  }

  // ws layout (bf16 elems), 56 MB total.
  __bf16* xb     = (__bf16*)d_ws;                       // 4096*1024
  __bf16* wqkvT  = xb + (size_t)Mrows * Cc;             // 3072*1024
  __bf16* wprojT = wqkvT + (size_t)N3 * Cc;             // 1024*1024
  __bf16* qkvp   = wprojT + (size_t)Cc * Cc;            // 4096*3072
  __bf16* vt     = qkvp + (size_t)Mrows * N3;           // 32*64*2048
  __bf16* obuf   = vt + (size_t)Bc * Hc * Dc * Tc;      // 4096*1024

  convert_x<<<(Mrows * Cc) / (256 * 8), 256, 0, stream>>>(x, xb, Mrows * Cc);
  transpose_perm<<<dim3(N3 / 32, Cc / 32), 256, 0, stream>>>(
      w_qkv, wqkvT, Cc, N3, 1);
  transpose_perm<<<dim3(Cc / 32, Cc / 32), 256, 0, stream>>>(
      w_proj, wprojT, Cc, Cc, 0);
  gemm_nt<false><<<dim3(N3 / 128, Mrows / 128), 256, 0, stream>>>(
      xb, wqkvT, qkvp, nullptr, Mrows, N3, Cc, N3);
  v_transpose<<<dim3(Tc / 32, 2, Bc * Hc), 256, 0, stream>>>(qkvp, vt);
  attn_kernel<<<dim3(Tc / 64, Bc * Hc), 256, 0, stream>>>(qkvp, vt, obuf);
  if (f32out) {
    gemm_nt<true><<<dim3(Cc / 128, Mrows / 128), 256, 0, stream>>>(
        obuf, wprojT, d_out, b_proj, Mrows, Cc, Cc, Cc);
  } else {
    gemm_nt<false><<<dim3(Cc / 128, Mrows / 128), 256, 0, stream>>>(
        obuf, wprojT, d_out, b_proj, Mrows, Cc, Cc, Cc);
  }
}